// Round 1
// 2449.921 us; speedup vs baseline: 1.2366x; 1.2366x over previous
//
#include <hip/hip_runtime.h>

#define TT 365
#define BB 512
#define DD 16
#define HH 256
#define SS 32

typedef __attribute__((ext_vector_type(8))) short short8;
typedef __attribute__((ext_vector_type(4))) float f32x4;
typedef unsigned long long u64;

// bf16 NaN x4 — unreachable as published data since |h|<=1 (sigm/tanh bounded)
#define SENT 0x7FC07FC07FC07FC0ULL

__device__ __host__ inline short f2bf(float f){
  union { float f; unsigned u; } v; v.f = f;
  unsigned r = v.u + 0x7FFFu + ((v.u >> 16) & 1u);
  return (short)(r >> 16);
}
__device__ inline float sigm(float x){ return 1.0f/(1.0f+__expf(-x)); }
__device__ inline float tanhx(float x){ return 2.0f/(1.0f+__expf(-2.0f*x)) - 1.0f; }

// A-fragment address (shorts) in an 8KB K=256 region for mfma_16x16x32 A-layout.
__device__ inline int fragAddr(int k, int m){
  return ((k>>5)*512) + ((((k&31)>>3)*16 + m)*8) + (k&7);
}

// ---------------- prep kernels ----------------
__global__ void prep_weights(const float* __restrict__ Wih0, const float* __restrict__ Whh0,
                             const float* __restrict__ Wih1, const float* __restrict__ Whh1,
                             short* __restrict__ Wb0, short* __restrict__ Wb1)
{
  int idx = blockIdx.x*blockDim.x + threadIdx.x;
  const int n0 = 16*36*512;
  const int n1 = 16*64*512;
  if (idx < n0){
    int frag = idx >> 9, pos = idx & 511;
    int lane = pos >> 3, jj = pos & 7;
    int slot = frag / 36, rem = frag % 36;
    int ks = rem >> 2, nt = rem & 3;
    int n = nt*256 + slot*16 + (lane & 15);
    float v = 0.0f;
    if (ks == 0){
      int k32 = (lane>>4)*8 + jj;
      if (k32 < 16) v = Wih0[n*16 + k32];
    } else {
      int k = (ks-1)*32 + (lane>>4)*8 + jj;
      v = Whh0[n*256 + k];
    }
    Wb0[idx] = f2bf(v);
  } else if (idx < n0 + n1){
    int e = idx - n0;
    int frag = e >> 9, pos = e & 511;
    int lane = pos >> 3, jj = pos & 7;
    int slot = frag >> 6, rem = frag & 63;
    int ks = rem >> 2, nt = rem & 3;
    int n = nt*256 + slot*16 + (lane & 15);
    int k = ks*32 + (lane>>4)*8 + jj;
    float v = (k < 256) ? Wih1[n*256 + k] : Whh1[n*256 + (k-256)];
    Wb1[e] = f2bf(v);
  }
}

__global__ void prep_h0(const float* __restrict__ xs, const float* __restrict__ Ws,
                        const float* __restrict__ bs, float* __restrict__ h0init)
{
  int i = blockIdx.x*blockDim.x + threadIdx.x;
  int b = i >> 8, jj = i & 255;
  float s = bs[jj];
  const float* xr = xs + b*SS;
  const float* wr = Ws + jj*SS;
#pragma unroll
  for (int q=0;q<SS;++q) s += xr[q]*wr[q];
  h0init[i] = s;
}

__global__ void prep_bias(const float* __restrict__ a0, const float* __restrict__ a1,
                          const float* __restrict__ a2, const float* __restrict__ a3,
                          float* __restrict__ b0o, float* __restrict__ b1o)
{
  int i = threadIdx.x + blockIdx.x*blockDim.x;
  if (i < 1024) b0o[i] = a0[i] + a1[i];
  else if (i < 2048) b1o[i-1024] = a2[i-1024] + a3[i-1024];
}

// zero out (atomicAdd target) + pre-poison both rings with sentinel
__global__ void prep_zero(float* __restrict__ out, u64* __restrict__ rings)
{
  int i = blockIdx.x*blockDim.x + threadIdx.x;
  if (i < BB*TT) out[i] = 0.0f;
  if (i < 393216) rings[i] = SENT;   // 2 rings x 1.5MB = 3MB / 8B
}

// ---------------- persistent fused LSTM ----------------
// 128 blocks x 256 threads; g = bid&31 (16 batch rows), c = bid>>5 (64 hidden cols).
// Weights register/AGPR-resident (F0[36]+F1[64] short8 = 400 regs/lane).
// Lag pipeline: superstep s runs L0@t=s and L1@t=s-1.
//
// Exchange protocol (data-embedded, consume-on-read):
//  - publish: 3 private copies per 8B word (one per consumer) via fire-and-forget
//    atomicExch (returns consumed late -> no downgrade, no local drain).
//  - consume: reader polls ITS copy with atomicExch(addr, SENT): RMW executes at
//    the coherence point (always fresh), and a hit consumes + re-poisons the word
//    in one atomic op. SENT = bf16 NaN x4, unreachable as data (|h|<=1).
//  - ring depth 2 is safe: writer reuses an address at s+2 only after consuming
//    the reader's s+1 publish, which is causally after the reader consumed
//    generation s from that very address (per-address L3 serialization).
//  - no flags, no vmcnt(0) drain, no acquire/buffer_inv, 2 barriers/step.
// Ring word layout (u64 units): (slt*32+g)*3072 + copy*1024 + k*4 + quad.
__global__ __launch_bounds__(256, 1) void lstm_fused(
    const short* __restrict__ Wb0, const short* __restrict__ Wb1,
    const float* __restrict__ h0i, const float* __restrict__ b0c,
    const float* __restrict__ b1c, const float* __restrict__ x,
    const float* __restrict__ Wo, const float* __restrict__ bo,
    u64* __restrict__ ring0, u64* __restrict__ ring1,
    unsigned* __restrict__ sinkbuf, float* __restrict__ out)
{
  __shared__ alignas(16) short AX[512];     // x_t frags, K=32 (k>=16 zero)
  __shared__ alignas(16) short AH0[4096];   // h0[t-1] frags, K=256
  __shared__ alignas(16) short AH1[4096];   // h1[t-2] frags, K=256
  __shared__ float outacc[16][4];
  __shared__ float outLDS[TT][16];          // per-block out partials (23.4 KB)

  const int tid  = threadIdx.x;
  const int w    = tid >> 6;
  const int lane = tid & 63;
  const int col16= lane & 15;
  const int quad = lane >> 4;
  const int c    = blockIdx.x >> 5;
  const int g    = blockIdx.x & 31;
  const int rowbase = g * 16;
  const int slot = c*4 + w;
  const int colg = slot*16 + col16;

  u64 sinkv = 0;

  // ---- register-resident weight fragments ----
  short8 F0[36], F1[64];
  {
    const short8* p0 = (const short8*)Wb0 + slot*36*64 + lane;
#pragma unroll
    for (int f=0; f<36; ++f) F0[f] = p0[f*64];
    const short8* p1 = (const short8*)Wb1 + slot*64*64 + lane;
#pragma unroll
    for (int f=0; f<64; ++f) F1[f] = p1[f*64];
  }
  float bia0[4], bia1[4];
#pragma unroll
  for (int nt=0; nt<4; ++nt){
    bia0[nt] = b0c[nt*256 + slot*16 + col16];
    bia1[nt] = b1c[nt*256 + slot*16 + col16];
  }
  const float wo = Wo[colg];

  // ---- init ----
  float c0[4], c1[4];
#pragma unroll
  for (int r=0; r<4; ++r){
    c0[r] = h0i[(rowbase + quad*4 + r)*HH + colg];
    c1[r] = c0[r];
  }
  for (int i = tid; i < 4096; i += 256){
    int m = i >> 8, k = i & 255;
    short v = f2bf(h0i[(rowbase+m)*HH + k]);
    AH0[fragAddr(k,m)] = v;
    AH1[fragAddr(k,m)] = v;
  }
  {
    int m = tid >> 4, d = tid & 15;
    AX[fragAddr(d, m)]      = f2bf(x[(rowbase+m)*TT*DD + d]);
    AX[fragAddr(16 + d, m)] = 0;
  }
  __syncthreads();

  const f32x4 zero = {0.0f,0.0f,0.0f,0.0f};
  const int qd = tid & 3;
  const int cl = (tid >> 2) & 63;

  for (int s=0; s<=TT; ++s){
    const bool doL0 = (s < TT);
    const bool doL1 = (s >= 1);

    // prefetch x_{s+1} (hidden under MFMAs)
    float xf = 0.0f;
    if (s+1 < TT){
      int m = tid >> 4, d = tid & 15;
      xf = x[(rowbase+m)*TT*DD + (s+1)*DD + d];
    }

    // ---- MFMA phase ----
    f32x4 acc0[4], acc1[4];
#pragma unroll
    for (int nt=0; nt<4; ++nt){ acc0[nt]=zero; acc1[nt]=zero; }
    if (doL0){
      short8 a = *(const short8*)(AX + lane*8);
#pragma unroll
      for (int nt=0; nt<4; ++nt)
        acc0[nt] = __builtin_amdgcn_mfma_f32_16x16x32_bf16(a, F0[nt], acc0[nt], 0,0,0);
    }
#pragma unroll
    for (int ks=0; ks<8; ++ks){
      short8 a = *(const short8*)(AH0 + ks*512 + lane*8);
      if (doL0){
#pragma unroll
        for (int nt=0; nt<4; ++nt)
          acc0[nt] = __builtin_amdgcn_mfma_f32_16x16x32_bf16(a, F0[(ks+1)*4+nt], acc0[nt], 0,0,0);
      }
      if (doL1){
#pragma unroll
        for (int nt=0; nt<4; ++nt)
          acc1[nt] = __builtin_amdgcn_mfma_f32_16x16x32_bf16(a, F1[ks*4+nt], acc1[nt], 0,0,0);
      }
    }
    if (doL1){
#pragma unroll
      for (int ks=0; ks<8; ++ks){
        short8 a = *(const short8*)(AH1 + ks*512 + lane*8);
#pragma unroll
        for (int nt=0; nt<4; ++nt)
          acc1[nt] = __builtin_amdgcn_mfma_f32_16x16x32_bf16(a, F1[32+ks*4+nt], acc1[nt], 0,0,0);
      }
    }

    // ---- epilogues + publish (fire-and-forget, 3 copies per word) ----
    float h0v[4], h1v[4], pr[4];
    u64 o0=0,o1=0,o2=0,o3=0,o4=0,o5=0;   // deferred-consumed publish returns
    if (doL0){
#pragma unroll
      for (int r=0; r<4; ++r){
        float iv = sigm (acc0[0][r] + bia0[0]);
        float fv = sigm (acc0[1][r] + bia0[1]);
        float gv = tanhx(acc0[2][r] + bia0[2]);
        float ov = sigm (acc0[3][r] + bia0[3]);
        float cc = fv*c0[r] + iv*gv;
        c0[r] = cc;
        h0v[r] = ov * tanhx(cc);
      }
      u64 pv; short* ps = (short*)&pv;
#pragma unroll
      for (int r=0; r<4; ++r) ps[r] = f2bf(h0v[r]);
      u64* b = ring0 + ((s&1)*32+g)*3072 + colg*4 + quad;
      o0 = __hip_atomic_exchange(b,        pv, __ATOMIC_RELAXED, __HIP_MEMORY_SCOPE_AGENT);
      o1 = __hip_atomic_exchange(b + 1024, pv, __ATOMIC_RELAXED, __HIP_MEMORY_SCOPE_AGENT);
      o2 = __hip_atomic_exchange(b + 2048, pv, __ATOMIC_RELAXED, __HIP_MEMORY_SCOPE_AGENT);
    }
    if (doL1){
#pragma unroll
      for (int r=0; r<4; ++r){
        float iv = sigm (acc1[0][r] + bia1[0]);
        float fv = sigm (acc1[1][r] + bia1[1]);
        float gv = tanhx(acc1[2][r] + bia1[2]);
        float ov = sigm (acc1[3][r] + bia1[3]);
        float cc = fv*c1[r] + iv*gv;
        c1[r] = cc;
        float h = ov * tanhx(cc);
        h1v[r] = h;
        pr[r] = h * wo;
      }
      if (s < TT){
        u64 pv; short* ps = (short*)&pv;
#pragma unroll
        for (int r=0; r<4; ++r) ps[r] = f2bf(h1v[r]);
        u64* b = ring1 + (((s-1)&1)*32+g)*3072 + colg*4 + quad;
        o3 = __hip_atomic_exchange(b,        pv, __ATOMIC_RELAXED, __HIP_MEMORY_SCOPE_AGENT);
        o4 = __hip_atomic_exchange(b + 1024, pv, __ATOMIC_RELAXED, __HIP_MEMORY_SCOPE_AGENT);
        o5 = __hip_atomic_exchange(b + 2048, pv, __ATOMIC_RELAXED, __HIP_MEMORY_SCOPE_AGENT);
      }
#pragma unroll
      for (int m=1; m<16; m<<=1){
#pragma unroll
        for (int r=0; r<4; ++r) pr[r] += __shfl_xor(pr[r], m, 64);
      }
      if (col16 == 0){
#pragma unroll
        for (int r=0; r<4; ++r) outacc[quad*4 + r][w] = pr[r];
      }
    }

    // ---- consume partner slices: poll own private copies with exch(SENT) ----
    u64 v0[3], v1[3];
    if (s < TT){
      u64* q0[3]; u64* q1[3];
#pragma unroll
      for (int pi=0; pi<3; ++pi){
        int k = (((c + 1 + pi) & 3) << 6) + cl;
        q0[pi] = ring0 + ((s&1)*32+g)*3072     + pi*1024 + k*4 + qd;
        q1[pi] = ring1 + (((s-1)&1)*32+g)*3072 + pi*1024 + k*4 + qd;
        v0[pi] = SENT; v1[pi] = SENT;
      }
      while (true){
        bool pending = false;
#pragma unroll
        for (int pi=0; pi<3; ++pi){
          if (v0[pi] == SENT)
            v0[pi] = __hip_atomic_exchange(q0[pi], SENT, __ATOMIC_RELAXED, __HIP_MEMORY_SCOPE_AGENT);
          if (doL1 && v1[pi] == SENT)
            v1[pi] = __hip_atomic_exchange(q1[pi], SENT, __ATOMIC_RELAXED, __HIP_MEMORY_SCOPE_AGENT);
        }
#pragma unroll
        for (int pi=0; pi<3; ++pi){
          pending |= (v0[pi] == SENT);
          if (doL1) pending |= (v1[pi] == SENT);
        }
        if (!pending) break;
      }
    }
    sinkv ^= o0 ^ o1 ^ o2 ^ o3 ^ o4 ^ o5;  // fold after polls: waits come free

    __syncthreads();  // B1: MFMA LDS reads + outacc writes complete

    if (doL1 && tid < 16)
      outLDS[s-1][tid] = outacc[tid][0] + outacc[tid][1] + outacc[tid][2] + outacc[tid][3];

    if (s < TT){
      // own h into LDS frags; stage x_{s+1}
#pragma unroll
      for (int r=0; r<4; ++r) AH0[fragAddr(colg, quad*4 + r)] = f2bf(h0v[r]);
      if (doL1){
#pragma unroll
        for (int r=0; r<4; ++r) AH1[fragAddr(colg, quad*4 + r)] = f2bf(h1v[r]);
      }
      if (s+1 < TT){
        int m = tid >> 4, d = tid & 15;
        AX[fragAddr(d, m)] = f2bf(xf);
      }
      // partner slices into LDS frags
#pragma unroll
      for (int pi=0; pi<3; ++pi){
        int k = (((c + 1 + pi) & 3) << 6) + cl;
        short* sv = (short*)&v0[pi];
#pragma unroll
        for (int r=0; r<4; ++r) AH0[fragAddr(k, qd*4 + r)] = sv[r];
        if (doL1){
          short* sw = (short*)&v1[pi];
#pragma unroll
          for (int r=0; r<4; ++r) AH1[fragAddr(k, qd*4 + r)] = sw[r];
        }
      }
    }
    __syncthreads();  // B3: LDS frags ready for next MFMA phase
  }

  // ---- final out accumulation (device-scope RMW, m20-verified) ----
  const float bos = bo[0];
  for (int i = tid; i < TT*16; i += 256){
    int t = i >> 4, row = i & 15;
    float v = outLDS[t][row];
    if (c == 0) v += bos;
    atomicAdd(&out[(rowbase + row)*TT + t], v);
  }
  sinkbuf[blockIdx.x] = (unsigned)(sinkv ^ (sinkv >> 32));  // consume exch results
}

// ---------------- launch ----------------
extern "C" void kernel_launch(void* const* d_in, const int* in_sizes, int n_in,
                              void* d_out, int out_size, void* d_ws, size_t ws_size,
                              hipStream_t stream)
{
  const float* x    = (const float*)d_in[0];
  const float* xs   = (const float*)d_in[1];
  const float* Wih0 = (const float*)d_in[2];
  const float* Whh0 = (const float*)d_in[3];
  const float* bih0 = (const float*)d_in[4];
  const float* bhh0 = (const float*)d_in[5];
  const float* Wih1 = (const float*)d_in[6];
  const float* Whh1 = (const float*)d_in[7];
  const float* bih1 = (const float*)d_in[8];
  const float* bhh1 = (const float*)d_in[9];
  const float* Ws   = (const float*)d_in[10];
  const float* bs   = (const float*)d_in[11];
  const float* Wo   = (const float*)d_in[12];
  const float* bo   = (const float*)d_in[13];
  float* out = (float*)d_out;

  char* ws = (char*)d_ws;
  short*    Wb0   = (short*)(ws);                // 589824
  short*    Wb1   = (short*)(ws + 589824);       // 1048576 -> 1638400
  float*    h0i   = (float*)(ws + 1638400);      // 524288  -> 2162688
  float*    b0cp  = (float*)(ws + 2162688);      // 4096    -> 2166784
  float*    b1cp  = (float*)(ws + 2166784);      // 4096    -> 2170880
  u64*      ring0 = (u64*)(ws + 2170880);        // 1572864 -> 3743744 (2 slots x 3 copies)
  u64*      ring1 = (u64*)(ws + 3743744);        // 1572864 -> 5316608
  unsigned* sinkb = (unsigned*)(ws + 5316608);   // 512     -> ~5.32 MB total

  int nswz = 16*36*512 + 16*64*512;
  hipLaunchKernelGGL(prep_weights, dim3((nswz+255)/256), dim3(256), 0, stream,
                     Wih0, Whh0, Wih1, Whh1, Wb0, Wb1);
  hipLaunchKernelGGL(prep_h0, dim3(512), dim3(256), 0, stream, xs, Ws, bs, h0i);
  hipLaunchKernelGGL(prep_bias, dim3(8), dim3(256), 0, stream, bih0, bhh0, bih1, bhh1, b0cp, b1cp);
  hipLaunchKernelGGL(prep_zero, dim3(1536), dim3(256), 0, stream, out, ring0);

  hipLaunchKernelGGL(lstm_fused, dim3(128), dim3(256), 0, stream,
                     Wb0, Wb1, h0i, b0cp, b1cp, x, Wo, bo,
                     ring0, ring1, sinkb, out);
}

// Round 2
// 2285.880 us; speedup vs baseline: 1.3253x; 1.0718x over previous
//
#include <hip/hip_runtime.h>

#define TT 365
#define BB 512
#define DD 16
#define HH 256
#define SS 32

typedef __attribute__((ext_vector_type(8))) short short8;
typedef __attribute__((ext_vector_type(4))) float f32x4;
typedef unsigned long long u64;

// Ring init poison: bf16 NaN x4 — bit14 set in both dwords (mismatches tag 0).
#define SENT 0x7FC07FC07FC07FC0ULL
// Generation-tag mask: bit14 of short0 and short2 (one per dword of the 8B word).
// |h| <= 1  =>  biased exp <= 127  =>  bit14 of every published bf16 is 0.
#define TAGM 0x0000400000004000ULL

__device__ __host__ inline short f2bf(float f){
  union { float f; unsigned u; } v; v.f = f;
  unsigned r = v.u + 0x7FFFu + ((v.u >> 16) & 1u);
  return (short)(r >> 16);
}
__device__ inline float sigm(float x){ return 1.0f/(1.0f+__expf(-x)); }
__device__ inline float tanhx(float x){ return 2.0f/(1.0f+__expf(-2.0f*x)) - 1.0f; }

// A-fragment address (shorts) in an 8KB K=256 region for mfma_16x16x32 A-layout.
__device__ inline int fragAddr(int k, int m){
  return ((k>>5)*512) + ((((k&31)>>3)*16 + m)*8) + (k&7);
}

// Cache-bypassing 8B store: lands at the device coherence point (no L1/L2 residency).
__device__ inline void pub_store(u64* p, u64 v){
  asm volatile("global_store_dwordx2 %0, %1, off sc0 sc1"
               :: "v"(p), "v"(v) : "memory");
}

// ---------------- prep kernels ----------------
__global__ void prep_weights(const float* __restrict__ Wih0, const float* __restrict__ Whh0,
                             const float* __restrict__ Wih1, const float* __restrict__ Whh1,
                             short* __restrict__ Wb0, short* __restrict__ Wb1)
{
  int idx = blockIdx.x*blockDim.x + threadIdx.x;
  const int n0 = 16*36*512;
  const int n1 = 16*64*512;
  if (idx < n0){
    int frag = idx >> 9, pos = idx & 511;
    int lane = pos >> 3, jj = pos & 7;
    int slot = frag / 36, rem = frag % 36;
    int ks = rem >> 2, nt = rem & 3;
    int n = nt*256 + slot*16 + (lane & 15);
    float v = 0.0f;
    if (ks == 0){
      int k32 = (lane>>4)*8 + jj;
      if (k32 < 16) v = Wih0[n*16 + k32];
    } else {
      int k = (ks-1)*32 + (lane>>4)*8 + jj;
      v = Whh0[n*256 + k];
    }
    Wb0[idx] = f2bf(v);
  } else if (idx < n0 + n1){
    int e = idx - n0;
    int frag = e >> 9, pos = e & 511;
    int lane = pos >> 3, jj = pos & 7;
    int slot = frag >> 6, rem = frag & 63;
    int ks = rem >> 2, nt = rem & 3;
    int n = nt*256 + slot*16 + (lane & 15);
    int k = ks*32 + (lane>>4)*8 + jj;
    float v = (k < 256) ? Wih1[n*256 + k] : Whh1[n*256 + (k-256)];
    Wb1[e] = f2bf(v);
  }
}

__global__ void prep_h0(const float* __restrict__ xs, const float* __restrict__ Ws,
                        const float* __restrict__ bs, float* __restrict__ h0init)
{
  int i = blockIdx.x*blockDim.x + threadIdx.x;
  int b = i >> 8, jj = i & 255;
  float s = bs[jj];
  const float* xr = xs + b*SS;
  const float* wr = Ws + jj*SS;
#pragma unroll
  for (int q=0;q<SS;++q) s += xr[q]*wr[q];
  h0init[i] = s;
}

__global__ void prep_bias(const float* __restrict__ a0, const float* __restrict__ a1,
                          const float* __restrict__ a2, const float* __restrict__ a3,
                          float* __restrict__ b0o, float* __restrict__ b1o)
{
  int i = threadIdx.x + blockIdx.x*blockDim.x;
  if (i < 1024) b0o[i] = a0[i] + a1[i];
  else if (i < 2048) b1o[i-1024] = a2[i-1024] + a3[i-1024];
}

// zero out (atomicAdd target) + pre-poison both rings (tag bits set => no false match)
__global__ void prep_zero(float* __restrict__ out, u64* __restrict__ rings)
{
  int i = blockIdx.x*blockDim.x + threadIdx.x;
  if (i < BB*TT) out[i] = 0.0f;
  if (i < 131072) rings[i] = SENT;   // 2 rings x 64 regions x 1024 words
}

// ---------------- persistent fused LSTM ----------------
// 128 blocks x 256 threads; g = bid&31 (16 batch rows), c = bid>>5 (64 hidden cols).
// Weights register/AGPR-resident (F0[36]+F1[64] short8 = 400 regs/lane).
// Lag pipeline: superstep s runs L0@t=s and L1@t=s-1.
//
// Exchange protocol (generation-tagged, read-only polling — NO atomics):
//  - publish: ONE plain sc0/sc1 (cache-bypassing, write-through) 8B store per ring.
//    Generation parity (s>>1)&1 is OR-ed into bit14 of BOTH dwords (bit14 of any
//    published bf16 is 0 since |h|<=1). Tag-in-data = no flag, no fence, no sink.
//  - poll: sc0/sc1 8B loads read fresh from the coherence point every iteration
//    (no stale-L2 risk, no buffer_inv, ZERO write traffic from polling).
//    Both dwords' tags must match => dword-level tearing detected.
//  - ring: slot (s&1) x parity ((s>>1)&1) = period-4 reuse. Mutual per-step
//    consumption bounds partner skew <= 1 step, so gen s vs s+-2 (tag flips) and
//    s+4 (unreachable) can never be confused. No re-poison needed.
// Ring word layout (u64 units): (slt*32+g)*1024 + colg*4 + quad.
__global__ __launch_bounds__(256, 1) void lstm_fused(
    const short* __restrict__ Wb0, const short* __restrict__ Wb1,
    const float* __restrict__ h0i, const float* __restrict__ b0c,
    const float* __restrict__ b1c, const float* __restrict__ x,
    const float* __restrict__ Wo, const float* __restrict__ bo,
    u64* __restrict__ ring0, u64* __restrict__ ring1,
    float* __restrict__ out)
{
  __shared__ alignas(16) short AX[512];     // x_t frags, K=32 (k>=16 zero)
  __shared__ alignas(16) short AH0[4096];   // h0[t-1] frags, K=256
  __shared__ alignas(16) short AH1[4096];   // h1[t-2] frags, K=256
  __shared__ float outacc[16][4];
  __shared__ float outLDS[TT][16];          // per-block out partials (23.4 KB)

  const int tid  = threadIdx.x;
  const int w    = tid >> 6;
  const int lane = tid & 63;
  const int col16= lane & 15;
  const int quad = lane >> 4;
  const int c    = blockIdx.x >> 5;
  const int g    = blockIdx.x & 31;
  const int rowbase = g * 16;
  const int slot = c*4 + w;
  const int colg = slot*16 + col16;

  // ---- register-resident weight fragments ----
  short8 F0[36], F1[64];
  {
    const short8* p0 = (const short8*)Wb0 + slot*36*64 + lane;
#pragma unroll
    for (int f=0; f<36; ++f) F0[f] = p0[f*64];
    const short8* p1 = (const short8*)Wb1 + slot*64*64 + lane;
#pragma unroll
    for (int f=0; f<64; ++f) F1[f] = p1[f*64];
  }
  float bia0[4], bia1[4];
#pragma unroll
  for (int nt=0; nt<4; ++nt){
    bia0[nt] = b0c[nt*256 + slot*16 + col16];
    bia1[nt] = b1c[nt*256 + slot*16 + col16];
  }
  const float wo = Wo[colg];

  // ---- init ----
  float c0[4], c1[4];
#pragma unroll
  for (int r=0; r<4; ++r){
    c0[r] = h0i[(rowbase + quad*4 + r)*HH + colg];
    c1[r] = c0[r];
  }
  for (int i = tid; i < 4096; i += 256){
    int m = i >> 8, k = i & 255;
    short v = f2bf(h0i[(rowbase+m)*HH + k]);
    AH0[fragAddr(k,m)] = v;
    AH1[fragAddr(k,m)] = v;
  }
  {
    int m = tid >> 4, d = tid & 15;
    AX[fragAddr(d, m)]      = f2bf(x[(rowbase+m)*TT*DD + d]);
    AX[fragAddr(16 + d, m)] = 0;
  }
  __syncthreads();

  const f32x4 zero = {0.0f,0.0f,0.0f,0.0f};
  const int qd = tid & 3;
  const int cl = (tid >> 2) & 63;

  for (int s=0; s<=TT; ++s){
    const bool doL0 = (s < TT);
    const bool doL1 = (s >= 1);
    const int  slot0 = s & 1;
    const int  slot1 = (s-1) & 1;
    const u64  want0 = ((s>>1)&1)     ? (u64)TAGM : 0ull;
    const u64  want1 = (((s-1)>>1)&1) ? (u64)TAGM : 0ull;

    // prefetch x_{s+1} (hidden under MFMAs)
    float xf = 0.0f;
    if (s+1 < TT){
      int m = tid >> 4, d = tid & 15;
      xf = x[(rowbase+m)*TT*DD + (s+1)*DD + d];
    }

    // ---- MFMA phase ----
    f32x4 acc0[4], acc1[4];
#pragma unroll
    for (int nt=0; nt<4; ++nt){ acc0[nt]=zero; acc1[nt]=zero; }
    if (doL0){
      short8 a = *(const short8*)(AX + lane*8);
#pragma unroll
      for (int nt=0; nt<4; ++nt)
        acc0[nt] = __builtin_amdgcn_mfma_f32_16x16x32_bf16(a, F0[nt], acc0[nt], 0,0,0);
    }
#pragma unroll
    for (int ks=0; ks<8; ++ks){
      short8 a = *(const short8*)(AH0 + ks*512 + lane*8);
      if (doL0){
#pragma unroll
        for (int nt=0; nt<4; ++nt)
          acc0[nt] = __builtin_amdgcn_mfma_f32_16x16x32_bf16(a, F0[(ks+1)*4+nt], acc0[nt], 0,0,0);
      }
      if (doL1){
#pragma unroll
        for (int nt=0; nt<4; ++nt)
          acc1[nt] = __builtin_amdgcn_mfma_f32_16x16x32_bf16(a, F1[ks*4+nt], acc1[nt], 0,0,0);
      }
    }
    if (doL1){
#pragma unroll
      for (int ks=0; ks<8; ++ks){
        short8 a = *(const short8*)(AH1 + ks*512 + lane*8);
#pragma unroll
        for (int nt=0; nt<4; ++nt)
          acc1[nt] = __builtin_amdgcn_mfma_f32_16x16x32_bf16(a, F1[32+ks*4+nt], acc1[nt], 0,0,0);
      }
    }

    // ---- epilogues + tagged publish (fire-and-forget, 1 copy) ----
    float h0v[4], h1v[4], pr[4];
    if (doL0){
#pragma unroll
      for (int r=0; r<4; ++r){
        float iv = sigm (acc0[0][r] + bia0[0]);
        float fv = sigm (acc0[1][r] + bia0[1]);
        float gv = tanhx(acc0[2][r] + bia0[2]);
        float ov = sigm (acc0[3][r] + bia0[3]);
        float cc = fv*c0[r] + iv*gv;
        c0[r] = cc;
        h0v[r] = ov * tanhx(cc);
      }
      u64 pv; short* ps = (short*)&pv;
#pragma unroll
      for (int r=0; r<4; ++r) ps[r] = f2bf(h0v[r]);
      pv |= want0;
      pub_store(ring0 + (slot0*32+g)*1024 + colg*4 + quad, pv);
    }
    if (doL1){
#pragma unroll
      for (int r=0; r<4; ++r){
        float iv = sigm (acc1[0][r] + bia1[0]);
        float fv = sigm (acc1[1][r] + bia1[1]);
        float gv = tanhx(acc1[2][r] + bia1[2]);
        float ov = sigm (acc1[3][r] + bia1[3]);
        float cc = fv*c1[r] + iv*gv;
        c1[r] = cc;
        float h = ov * tanhx(cc);
        h1v[r] = h;
        pr[r] = h * wo;
      }
      if (s < TT){
        u64 pv; short* ps = (short*)&pv;
#pragma unroll
        for (int r=0; r<4; ++r) ps[r] = f2bf(h1v[r]);
        pv |= want1;
        pub_store(ring1 + (slot1*32+g)*1024 + colg*4 + quad, pv);
      }
#pragma unroll
      for (int m=1; m<16; m<<=1){
#pragma unroll
        for (int r=0; r<4; ++r) pr[r] += __shfl_xor(pr[r], m, 64);
      }
      if (col16 == 0){
#pragma unroll
        for (int r=0; r<4; ++r) outacc[quad*4 + r][w] = pr[r];
      }
    }

    // ---- consume partner slices: read-only tagged polling ----
    u64 v0a=0,v0b=0,v0c=0,v1a=0,v1b=0,v1c=0;
    if (s < TT){
      const int k0 = (((c + 1) & 3) << 6) + cl;
      const int k1 = (((c + 2) & 3) << 6) + cl;
      const int k2 = (((c + 3) & 3) << 6) + cl;
      const u64* q0a = ring0 + (slot0*32+g)*1024 + k0*4 + qd;
      const u64* q0b = ring0 + (slot0*32+g)*1024 + k1*4 + qd;
      const u64* q0c = ring0 + (slot0*32+g)*1024 + k2*4 + qd;
      const u64* q1a = ring1 + (slot1*32+g)*1024 + k0*4 + qd;
      const u64* q1b = ring1 + (slot1*32+g)*1024 + k1*4 + qd;
      const u64* q1c = ring1 + (slot1*32+g)*1024 + k2*4 + qd;
      bool p0a=false,p0b=false,p0c=false;
      bool p1a=!doL1, p1b=!doL1, p1c=!doL1;
      while (true){
        u64 t0,t1,t2,t3,t4,t5;
        asm volatile(
          "global_load_dwordx2 %0, %6, off sc0 sc1\n\t"
          "global_load_dwordx2 %1, %7, off sc0 sc1\n\t"
          "global_load_dwordx2 %2, %8, off sc0 sc1\n\t"
          "global_load_dwordx2 %3, %9, off sc0 sc1\n\t"
          "global_load_dwordx2 %4, %10, off sc0 sc1\n\t"
          "global_load_dwordx2 %5, %11, off sc0 sc1\n\t"
          "s_waitcnt vmcnt(0)"
          : "=&v"(t0),"=&v"(t1),"=&v"(t2),"=&v"(t3),"=&v"(t4),"=&v"(t5)
          : "v"(q0a),"v"(q0b),"v"(q0c),"v"(q1a),"v"(q1b),"v"(q1c)
          : "memory");
        if (!p0a && (t0 & TAGM) == want0){ v0a = t0 & ~(u64)TAGM; p0a = true; }
        if (!p0b && (t1 & TAGM) == want0){ v0b = t1 & ~(u64)TAGM; p0b = true; }
        if (!p0c && (t2 & TAGM) == want0){ v0c = t2 & ~(u64)TAGM; p0c = true; }
        if (!p1a && (t3 & TAGM) == want1){ v1a = t3 & ~(u64)TAGM; p1a = true; }
        if (!p1b && (t4 & TAGM) == want1){ v1b = t4 & ~(u64)TAGM; p1b = true; }
        if (!p1c && (t5 & TAGM) == want1){ v1c = t5 & ~(u64)TAGM; p1c = true; }
        if (p0a & p0b & p0c & p1a & p1b & p1c) break;
      }
    }

    __syncthreads();  // B1: MFMA LDS reads + outacc writes complete

    if (doL1 && tid < 16)
      outLDS[s-1][tid] = outacc[tid][0] + outacc[tid][1] + outacc[tid][2] + outacc[tid][3];

    if (s < TT){
      // own h into LDS frags; stage x_{s+1}
#pragma unroll
      for (int r=0; r<4; ++r) AH0[fragAddr(colg, quad*4 + r)] = f2bf(h0v[r]);
      if (doL1){
#pragma unroll
        for (int r=0; r<4; ++r) AH1[fragAddr(colg, quad*4 + r)] = f2bf(h1v[r]);
      }
      if (s+1 < TT){
        int m = tid >> 4, d = tid & 15;
        AX[fragAddr(d, m)] = f2bf(xf);
      }
      // partner slices into LDS frags
      const int k0 = (((c + 1) & 3) << 6) + cl;
      const int k1 = (((c + 2) & 3) << 6) + cl;
      const int k2 = (((c + 3) & 3) << 6) + cl;
      {
        short* sv = (short*)&v0a;
#pragma unroll
        for (int r=0; r<4; ++r) AH0[fragAddr(k0, qd*4 + r)] = sv[r];
        sv = (short*)&v0b;
#pragma unroll
        for (int r=0; r<4; ++r) AH0[fragAddr(k1, qd*4 + r)] = sv[r];
        sv = (short*)&v0c;
#pragma unroll
        for (int r=0; r<4; ++r) AH0[fragAddr(k2, qd*4 + r)] = sv[r];
      }
      if (doL1){
        short* sw = (short*)&v1a;
#pragma unroll
        for (int r=0; r<4; ++r) AH1[fragAddr(k0, qd*4 + r)] = sw[r];
        sw = (short*)&v1b;
#pragma unroll
        for (int r=0; r<4; ++r) AH1[fragAddr(k1, qd*4 + r)] = sw[r];
        sw = (short*)&v1c;
#pragma unroll
        for (int r=0; r<4; ++r) AH1[fragAddr(k2, qd*4 + r)] = sw[r];
      }
    }
    __syncthreads();  // B3: LDS frags ready for next MFMA phase
  }

  // ---- final out accumulation (device-scope RMW, m20-verified) ----
  const float bos = bo[0];
  for (int i = tid; i < TT*16; i += 256){
    int t = i >> 4, row = i & 15;
    float v = outLDS[t][row];
    if (c == 0) v += bos;
    atomicAdd(&out[(rowbase + row)*TT + t], v);
  }
}

// ---------------- launch ----------------
extern "C" void kernel_launch(void* const* d_in, const int* in_sizes, int n_in,
                              void* d_out, int out_size, void* d_ws, size_t ws_size,
                              hipStream_t stream)
{
  const float* x    = (const float*)d_in[0];
  const float* xs   = (const float*)d_in[1];
  const float* Wih0 = (const float*)d_in[2];
  const float* Whh0 = (const float*)d_in[3];
  const float* bih0 = (const float*)d_in[4];
  const float* bhh0 = (const float*)d_in[5];
  const float* Wih1 = (const float*)d_in[6];
  const float* Whh1 = (const float*)d_in[7];
  const float* bih1 = (const float*)d_in[8];
  const float* bhh1 = (const float*)d_in[9];
  const float* Ws   = (const float*)d_in[10];
  const float* bs   = (const float*)d_in[11];
  const float* Wo   = (const float*)d_in[12];
  const float* bo   = (const float*)d_in[13];
  float* out = (float*)d_out;

  char* ws = (char*)d_ws;
  short*    Wb0   = (short*)(ws);                // 589824
  short*    Wb1   = (short*)(ws + 589824);       // 1048576 -> 1638400
  float*    h0i   = (float*)(ws + 1638400);      // 524288  -> 2162688
  float*    b0cp  = (float*)(ws + 2162688);      // 4096    -> 2166784
  float*    b1cp  = (float*)(ws + 2166784);      // 4096    -> 2170880
  u64*      ring0 = (u64*)(ws + 2170880);        // 524288  -> 2695168 (2 slots)
  u64*      ring1 = (u64*)(ws + 2695168);        // 524288  -> 3219456 (~3.22 MB total)

  int nswz = 16*36*512 + 16*64*512;
  hipLaunchKernelGGL(prep_weights, dim3((nswz+255)/256), dim3(256), 0, stream,
                     Wih0, Whh0, Wih1, Whh1, Wb0, Wb1);
  hipLaunchKernelGGL(prep_h0, dim3(512), dim3(256), 0, stream, xs, Ws, bs, h0i);
  hipLaunchKernelGGL(prep_bias, dim3(8), dim3(256), 0, stream, bih0, bhh0, bih1, bhh1, b0cp, b1cp);
  hipLaunchKernelGGL(prep_zero, dim3(1024), dim3(256), 0, stream, out, ring0);

  hipLaunchKernelGGL(lstm_fused, dim3(128), dim3(256), 0, stream,
                     Wb0, Wb1, h0i, b0cp, b1cp, x, Wo, bo,
                     ring0, ring1, out);
}

// Round 3
// 1645.395 us; speedup vs baseline: 1.8412x; 1.3893x over previous
//
#include <hip/hip_runtime.h>

#define TT 365
#define BB 512
#define DD 16
#define HH 256
#define SS 32

typedef __attribute__((ext_vector_type(8))) short short8;
typedef __attribute__((ext_vector_type(4))) float f32x4;
typedef __attribute__((ext_vector_type(4))) unsigned u32x4;
typedef unsigned long long u64;

// Ring init poison: bf16 NaN x4 — bit14 set in both dwords (mismatches tag 0).
#define SENT 0x7FC07FC07FC07FC0ULL
// Generation-tag: bit14 of each dword. |h|<=1 => bit14 of any published bf16 is 0.
#define TB32 0x00004000u

__device__ __host__ inline short f2bf(float f){
  union { float f; unsigned u; } v; v.f = f;
  unsigned r = v.u + 0x7FFFu + ((v.u >> 16) & 1u);
  return (short)(r >> 16);
}
__device__ inline float sigm(float x){ return 1.0f/(1.0f+__expf(-x)); }
__device__ inline float tanhx(float x){ return 2.0f/(1.0f+__expf(-2.0f*x)) - 1.0f; }

// A-fragment address (shorts) in an 8KB K=256 region for mfma_16x16x32 A-layout.
__device__ inline int fragAddr(int k, int m){
  return ((k>>5)*512) + ((((k&31)>>3)*16 + m)*8) + (k&7);
}

// Cache-bypassing 8B store: lands at the device coherence point.
__device__ inline void pub_store(u64* p, u64 v){
  asm volatile("global_store_dwordx2 %0, %1, off sc0 sc1"
               :: "v"(p), "v"(v) : "memory");
}

// ---------------- prep kernels ----------------
__global__ void prep_weights(const float* __restrict__ Wih0, const float* __restrict__ Whh0,
                             const float* __restrict__ Wih1, const float* __restrict__ Whh1,
                             short* __restrict__ Wb0, short* __restrict__ Wb1)
{
  int idx = blockIdx.x*blockDim.x + threadIdx.x;
  const int n0 = 16*36*512;
  const int n1 = 16*64*512;
  if (idx < n0){
    int frag = idx >> 9, pos = idx & 511;
    int lane = pos >> 3, jj = pos & 7;
    int slot = frag / 36, rem = frag % 36;
    int ks = rem >> 2, nt = rem & 3;
    int n = nt*256 + slot*16 + (lane & 15);
    float v = 0.0f;
    if (ks == 0){
      int k32 = (lane>>4)*8 + jj;
      if (k32 < 16) v = Wih0[n*16 + k32];
    } else {
      int k = (ks-1)*32 + (lane>>4)*8 + jj;
      v = Whh0[n*256 + k];
    }
    Wb0[idx] = f2bf(v);
  } else if (idx < n0 + n1){
    int e = idx - n0;
    int frag = e >> 9, pos = e & 511;
    int lane = pos >> 3, jj = pos & 7;
    int slot = frag >> 6, rem = frag & 63;
    int ks = rem >> 2, nt = rem & 3;
    int n = nt*256 + slot*16 + (lane & 15);
    int k = ks*32 + (lane>>4)*8 + jj;
    float v = (k < 256) ? Wih1[n*256 + k] : Whh1[n*256 + (k-256)];
    Wb1[e] = f2bf(v);
  }
}

__global__ void prep_h0(const float* __restrict__ xs, const float* __restrict__ Ws,
                        const float* __restrict__ bs, float* __restrict__ h0init)
{
  int i = blockIdx.x*blockDim.x + threadIdx.x;
  int b = i >> 8, jj = i & 255;
  float s = bs[jj];
  const float* xr = xs + b*SS;
  const float* wr = Ws + jj*SS;
#pragma unroll
  for (int q=0;q<SS;++q) s += xr[q]*wr[q];
  h0init[i] = s;
}

__global__ void prep_bias(const float* __restrict__ a0, const float* __restrict__ a1,
                          const float* __restrict__ a2, const float* __restrict__ a3,
                          float* __restrict__ b0o, float* __restrict__ b1o)
{
  int i = threadIdx.x + blockIdx.x*blockDim.x;
  if (i < 1024) b0o[i] = a0[i] + a1[i];
  else if (i < 2048) b1o[i-1024] = a2[i-1024] + a3[i-1024];
}

// zero out (atomicAdd target) + pre-poison ring (tag bits set => no false match)
__global__ void prep_zero(float* __restrict__ out, u64* __restrict__ ring)
{
  int i = blockIdx.x*blockDim.x + threadIdx.x;
  if (i < BB*TT) out[i] = 0.0f;
  if (i < 131072) ring[i] = SENT;   // 2 slots x 32 g x 2048 u64 = 1MB
}

// ---------------- persistent fused LSTM ----------------
// 128 blocks x 256 threads; g = bid&31 (16 batch rows), c = bid>>5 (64 hidden cols).
// Weights register/AGPR-resident (F0[36]+F1[64] short8 = 400 regs/lane).
// Lag pipeline: superstep s runs L0@t=s and L1@t=s-1.
//
// Critical-path-minimized schedule (ONE barrier/step, double-buffered LDS frags):
//   L0 MFMAs -> L0 epi -> publish h0(s) EARLY          (h0 recurrence = only true serial dep)
//   L1 MFMAs -> L1 epi -> publish h1(s-1) -> out-reduce (all inside partners' hiding window)
//   issue poll round-0 -> own frag writes (buf p^1) -> poll until tagged -> partner frag
//   writes (buf p^1) -> BAR -> out atomicAdd
//
// Packet(s) = {h0(s), h1(s-1)} in ADJACENT u64s: slot s&1, tag parity (s>>1)&1 in
// bit14 of every dword. One 16B poll load per partner (3 total). Period-4 address
// reuse is safe: mutual per-step consumption bounds skew <= 1 step (causality chain
// through publishes), so parity disambiguates +-2 and +-4 is unreachable.
// s=0's h1 word is stored as 0 (tags clear) so stale garbage can never satisfy
// packet(2)'s parity-1 check.
// Ring word layout (u64): (slot*32+g)*2048 + (k*4+quad)*2 + {0:h0, 1:h1}.
__global__ __launch_bounds__(256, 1) void lstm_fused(
    const short* __restrict__ Wb0, const short* __restrict__ Wb1,
    const float* __restrict__ h0i, const float* __restrict__ b0c,
    const float* __restrict__ b1c, const float* __restrict__ x,
    const float* __restrict__ Wo, const float* __restrict__ bo,
    u64* __restrict__ ring, float* __restrict__ out)
{
  __shared__ alignas(16) short AX[2][512];    // x_t frags, K=32 (k>=16 zero)
  __shared__ alignas(16) short AH0[2][4096];  // h0[t-1] frags, K=256 (double-buffered)
  __shared__ alignas(16) short AH1[2][4096];  // h1[t-2] frags, K=256 (double-buffered)
  __shared__ float outacc[2][16][4];

  const int tid  = threadIdx.x;
  const int w    = tid >> 6;
  const int lane = tid & 63;
  const int col16= lane & 15;
  const int quad = lane >> 4;
  const int c    = blockIdx.x >> 5;
  const int g    = blockIdx.x & 31;
  const int rowbase = g * 16;
  const int slot = c*4 + w;
  const int colg = slot*16 + col16;

  // ---- register-resident weight fragments ----
  short8 F0[36], F1[64];
  {
    const short8* p0 = (const short8*)Wb0 + slot*36*64 + lane;
#pragma unroll
    for (int f=0; f<36; ++f) F0[f] = p0[f*64];
    const short8* p1 = (const short8*)Wb1 + slot*64*64 + lane;
#pragma unroll
    for (int f=0; f<64; ++f) F1[f] = p1[f*64];
  }
  float bia0[4], bia1[4];
#pragma unroll
  for (int nt=0; nt<4; ++nt){
    bia0[nt] = b0c[nt*256 + slot*16 + col16];
    bia1[nt] = b1c[nt*256 + slot*16 + col16];
  }
  const float wo = Wo[colg];
  const float bos = bo[0];

  // ---- init (both buffers) ----
  float c0[4], c1[4];
#pragma unroll
  for (int r=0; r<4; ++r){
    c0[r] = h0i[(rowbase + quad*4 + r)*HH + colg];
    c1[r] = c0[r];
  }
  for (int i = tid; i < 4096; i += 256){
    int m = i >> 8, k = i & 255;
    short v = f2bf(h0i[(rowbase+m)*HH + k]);
    int a = fragAddr(k,m);
    AH0[0][a] = v; AH0[1][a] = v;
    AH1[0][a] = v; AH1[1][a] = v;
  }
  {
    int m = tid >> 4, d = tid & 15;
    short v = f2bf(x[(rowbase+m)*TT*DD + d]);
    AX[0][fragAddr(d, m)] = v;      AX[1][fragAddr(d, m)] = v;
    AX[0][fragAddr(16 + d, m)] = 0; AX[1][fragAddr(16 + d, m)] = 0;
  }
  __syncthreads();

  const f32x4 zero = {0.0f,0.0f,0.0f,0.0f};
  const int qd = tid & 3;
  const int cl = (tid >> 2) & 63;
  const int ka = (((c + 1) & 3) << 6) + cl;
  const int kb = (((c + 2) & 3) << 6) + cl;
  const int kc = (((c + 3) & 3) << 6) + cl;

  for (int s=0; s<=TT; ++s){
    const bool doL0 = (s < TT);
    const bool doL1 = (s >= 1);
    const int  p = s & 1;
    const unsigned wd = ((s>>1)&1) ? TB32 : 0u;
    const u64  want = ((u64)wd << 32) | wd;
    short* ax   = AX[p];   short* ah0   = AH0[p];   short* ah1   = AH1[p];
    short* ax_n = AX[p^1]; short* ah0_n = AH0[p^1]; short* ah1_n = AH1[p^1];
    u64* rbase = ring + (p*32+g)*2048;

    // prefetch x_{s+1} (hidden under MFMAs)
    float xf = 0.0f;
    if (s+1 < TT){
      int m = tid >> 4, d = tid & 15;
      xf = x[(rowbase+m)*TT*DD + (s+1)*DD + d];
    }

    // ---- L0 first: MFMAs -> epilogue -> EARLY publish of h0(s) ----
    u64 pv0 = 0, pv1 = 0;
    float h0v[4];
    if (doL0){
      f32x4 acc0[4];
#pragma unroll
      for (int nt=0; nt<4; ++nt) acc0[nt] = zero;
      {
        short8 a = *(const short8*)(ax + lane*8);
#pragma unroll
        for (int nt=0; nt<4; ++nt)
          acc0[nt] = __builtin_amdgcn_mfma_f32_16x16x32_bf16(a, F0[nt], acc0[nt], 0,0,0);
      }
#pragma unroll
      for (int ks=0; ks<8; ++ks){
        short8 a = *(const short8*)(ah0 + ks*512 + lane*8);
#pragma unroll
        for (int nt=0; nt<4; ++nt)
          acc0[nt] = __builtin_amdgcn_mfma_f32_16x16x32_bf16(a, F0[(ks+1)*4+nt], acc0[nt], 0,0,0);
      }
#pragma unroll
      for (int r=0; r<4; ++r){
        float iv = sigm (acc0[0][r] + bia0[0]);
        float fv = sigm (acc0[1][r] + bia0[1]);
        float gv = tanhx(acc0[2][r] + bia0[2]);
        float ov = sigm (acc0[3][r] + bia0[3]);
        float cc = fv*c0[r] + iv*gv;
        c0[r] = cc;
        h0v[r] = ov * tanhx(cc);
      }
      short* ps = (short*)&pv0;
#pragma unroll
      for (int r=0; r<4; ++r) ps[r] = f2bf(h0v[r]);
      pub_store(rbase + (colg*4+quad)*2, pv0 | want);   // h0 word, EARLY
    }

    // ---- L1: MFMAs -> epilogue -> publish h1(s-1) -> out-reduce ----
    if (doL1){
      f32x4 acc1[4];
#pragma unroll
      for (int nt=0; nt<4; ++nt) acc1[nt] = zero;
#pragma unroll
      for (int ks=0; ks<8; ++ks){
        short8 a = *(const short8*)(ah0 + ks*512 + lane*8);
#pragma unroll
        for (int nt=0; nt<4; ++nt)
          acc1[nt] = __builtin_amdgcn_mfma_f32_16x16x32_bf16(a, F1[ks*4+nt], acc1[nt], 0,0,0);
      }
#pragma unroll
      for (int ks=0; ks<8; ++ks){
        short8 a = *(const short8*)(ah1 + ks*512 + lane*8);
#pragma unroll
        for (int nt=0; nt<4; ++nt)
          acc1[nt] = __builtin_amdgcn_mfma_f32_16x16x32_bf16(a, F1[32+ks*4+nt], acc1[nt], 0,0,0);
      }
      float pr[4];
#pragma unroll
      for (int r=0; r<4; ++r){
        float iv = sigm (acc1[0][r] + bia1[0]);
        float fv = sigm (acc1[1][r] + bia1[1]);
        float gv = tanhx(acc1[2][r] + bia1[2]);
        float ov = sigm (acc1[3][r] + bia1[3]);
        float cc = fv*c1[r] + iv*gv;
        c1[r] = cc;
        float h = ov * tanhx(cc);
        pr[r] = h * wo;
        ((short*)&pv1)[r] = f2bf(h);
      }
      if (s < TT)
        pub_store(rbase + (colg*4+quad)*2 + 1, pv1 | want);  // h1 word
#pragma unroll
      for (int m=1; m<16; m<<=1){
#pragma unroll
        for (int r=0; r<4; ++r) pr[r] += __shfl_xor(pr[r], m, 64);
      }
      if (col16 == 0){
#pragma unroll
        for (int r=0; r<4; ++r) outacc[p][quad*4 + r][w] = pr[r];
      }
    } else if (s < TT){
      // s==0: store tag-CLEAR zero so stale garbage can't match packet(2)'s parity-1.
      pub_store(rbase + (colg*4+quad)*2 + 1, 0ull);
    }

    // ---- issue poll round-0, then own-frag writes overlap the first RTT ----
    u64 w0a=0,w1a=0,w0b=0,w1b=0,w0c=0,w1c=0;
    if (s < TT){
      const u64* qa = rbase + (ka*4+qd)*2;
      const u64* qb = rbase + (kb*4+qd)*2;
      const u64* qc = rbase + (kc*4+qd)*2;
      u32x4 ta, tb, tc;
      asm volatile(
        "global_load_dwordx4 %0, %3, off sc0 sc1\n\t"
        "global_load_dwordx4 %1, %4, off sc0 sc1\n\t"
        "global_load_dwordx4 %2, %5, off sc0 sc1"
        : "=&v"(ta),"=&v"(tb),"=&v"(tc)
        : "v"(qa),"v"(qb),"v"(qc)
        : "memory");

      // own frags into next buffer (no race: others read buf p)
#pragma unroll
      for (int r=0; r<4; ++r)
        ah0_n[fragAddr(colg, quad*4 + r)] = (short)(pv0 >> (16*r));
      if (doL1){
#pragma unroll
        for (int r=0; r<4; ++r)
          ah1_n[fragAddr(colg, quad*4 + r)] = (short)(pv1 >> (16*r));
      }
      if (s+1 < TT){
        int m = tid >> 4, d = tid & 15;
        ax_n[fragAddr(d, m)] = f2bf(xf);
      }

      bool f0a=false, f0b=false, f0c=false;
      bool f1a=!doL1, f1b=!doL1, f1c=!doL1;
      while (true){
        asm volatile("s_waitcnt vmcnt(0)" ::: "memory");
        if (!f0a && (ta.x&TB32)==wd && (ta.y&TB32)==wd){
          w0a = (((u64)(ta.y&~TB32))<<32)|(ta.x&~TB32); f0a=true; }
        if (!f1a && (ta.z&TB32)==wd && (ta.w&TB32)==wd){
          w1a = (((u64)(ta.w&~TB32))<<32)|(ta.z&~TB32); f1a=true; }
        if (!f0b && (tb.x&TB32)==wd && (tb.y&TB32)==wd){
          w0b = (((u64)(tb.y&~TB32))<<32)|(tb.x&~TB32); f0b=true; }
        if (!f1b && (tb.z&TB32)==wd && (tb.w&TB32)==wd){
          w1b = (((u64)(tb.w&~TB32))<<32)|(tb.z&~TB32); f1b=true; }
        if (!f0c && (tc.x&TB32)==wd && (tc.y&TB32)==wd){
          w0c = (((u64)(tc.y&~TB32))<<32)|(tc.x&~TB32); f0c=true; }
        if (!f1c && (tc.z&TB32)==wd && (tc.w&TB32)==wd){
          w1c = (((u64)(tc.w&~TB32))<<32)|(tc.z&~TB32); f1c=true; }
        if (f0a & f1a & f0b & f1b & f0c & f1c) break;
        asm volatile(
          "global_load_dwordx4 %0, %3, off sc0 sc1\n\t"
          "global_load_dwordx4 %1, %4, off sc0 sc1\n\t"
          "global_load_dwordx4 %2, %5, off sc0 sc1"
          : "=&v"(ta),"=&v"(tb),"=&v"(tc)
          : "v"(qa),"v"(qb),"v"(qc)
          : "memory");
      }

      // partner frags into next buffer
      {
        short* sv = (short*)&w0a;
#pragma unroll
        for (int r=0; r<4; ++r) ah0_n[fragAddr(ka, qd*4 + r)] = sv[r];
        sv = (short*)&w0b;
#pragma unroll
        for (int r=0; r<4; ++r) ah0_n[fragAddr(kb, qd*4 + r)] = sv[r];
        sv = (short*)&w0c;
#pragma unroll
        for (int r=0; r<4; ++r) ah0_n[fragAddr(kc, qd*4 + r)] = sv[r];
      }
      if (doL1){
        short* sw = (short*)&w1a;
#pragma unroll
        for (int r=0; r<4; ++r) ah1_n[fragAddr(ka, qd*4 + r)] = sw[r];
        sw = (short*)&w1b;
#pragma unroll
        for (int r=0; r<4; ++r) ah1_n[fragAddr(kb, qd*4 + r)] = sw[r];
        sw = (short*)&w1c;
#pragma unroll
        for (int r=0; r<4; ++r) ah1_n[fragAddr(kc, qd*4 + r)] = sw[r];
      }
    }

    __syncthreads();

    // ---- out partials: t = s-1 (device-scope RMW, m20-verified) ----
    if (doL1 && tid < 16){
      float v = outacc[p][tid][0] + outacc[p][tid][1]
              + outacc[p][tid][2] + outacc[p][tid][3];
      if (c == 0) v += bos;
      atomicAdd(&out[(rowbase + tid)*TT + (s-1)], v);
    }
  }
}

// ---------------- launch ----------------
extern "C" void kernel_launch(void* const* d_in, const int* in_sizes, int n_in,
                              void* d_out, int out_size, void* d_ws, size_t ws_size,
                              hipStream_t stream)
{
  const float* x    = (const float*)d_in[0];
  const float* xs   = (const float*)d_in[1];
  const float* Wih0 = (const float*)d_in[2];
  const float* Whh0 = (const float*)d_in[3];
  const float* bih0 = (const float*)d_in[4];
  const float* bhh0 = (const float*)d_in[5];
  const float* Wih1 = (const float*)d_in[6];
  const float* Whh1 = (const float*)d_in[7];
  const float* bih1 = (const float*)d_in[8];
  const float* bhh1 = (const float*)d_in[9];
  const float* Ws   = (const float*)d_in[10];
  const float* bs   = (const float*)d_in[11];
  const float* Wo   = (const float*)d_in[12];
  const float* bo   = (const float*)d_in[13];
  float* out = (float*)d_out;

  char* ws = (char*)d_ws;
  short*    Wb0   = (short*)(ws);                // 589824
  short*    Wb1   = (short*)(ws + 589824);       // 1048576 -> 1638400
  float*    h0i   = (float*)(ws + 1638400);      // 524288  -> 2162688
  float*    b0cp  = (float*)(ws + 2162688);      // 4096    -> 2166784
  float*    b1cp  = (float*)(ws + 2166784);      // 4096    -> 2170880
  u64*      ring  = (u64*)(ws + 2170880);        // 1048576 -> 3219456 (~3.22 MB)

  int nswz = 16*36*512 + 16*64*512;
  hipLaunchKernelGGL(prep_weights, dim3((nswz+255)/256), dim3(256), 0, stream,
                     Wih0, Whh0, Wih1, Whh1, Wb0, Wb1);
  hipLaunchKernelGGL(prep_h0, dim3(512), dim3(256), 0, stream, xs, Ws, bs, h0i);
  hipLaunchKernelGGL(prep_bias, dim3(8), dim3(256), 0, stream, bih0, bhh0, bih1, bhh1, b0cp, b1cp);
  hipLaunchKernelGGL(prep_zero, dim3(1024), dim3(256), 0, stream, out, ring);

  hipLaunchKernelGGL(lstm_fused, dim3(128), dim3(256), 0, stream,
                     Wb0, Wb1, h0i, b0cp, b1cp, x, Wo, bo, ring, out);
}